// Round 1
// baseline (136.075 us; speedup 1.0000x reference)
//
#include <hip/hip_runtime.h>
#include <math.h>

#define SEQ   64
#define DIM   512
#define NOSC  14
#define NPAD  16
#define NSTEP 100

// ---------------- Kernel 1: mean-pool over tokens + projection to theta0 ----
// One block per batch row. 256 threads.
// Threads t: f = t & 127 (float4 feature chunk), shalf = t >> 7 (s in [0,32) or [32,64)).
__global__ __launch_bounds__(256)
void pool_proj_kernel(const float* __restrict__ x,
                      const float* __restrict__ W_in,
                      const float* __restrict__ b_in,
                      float* __restrict__ theta0)
{
    const int b = blockIdx.x;
    const int t = threadIdx.x;
    const int f = t & 127;
    const int shalf = t >> 7;

    const float4* xv = reinterpret_cast<const float4*>(x + (size_t)b * (SEQ * DIM));

    float4 acc = make_float4(0.f, 0.f, 0.f, 0.f);
    const int s0 = shalf * 32;
#pragma unroll 8
    for (int s = s0; s < s0 + 32; ++s) {
        float4 v = xv[s * (DIM / 4) + f];
        acc.x += v.x; acc.y += v.y; acc.z += v.z; acc.w += v.w;
    }

    __shared__ float  meanv[DIM];
    __shared__ float4 part[128];
    __shared__ float  pp[NOSC][16];

    if (shalf == 1) part[f] = acc;
    __syncthreads();
    if (shalf == 0) {
        float4 o = part[f];
        const float inv = 1.0f / (float)SEQ;
        meanv[4 * f + 0] = (acc.x + o.x) * inv;
        meanv[4 * f + 1] = (acc.y + o.y) * inv;
        meanv[4 * f + 2] = (acc.z + o.z) * inv;
        meanv[4 * f + 3] = (acc.w + o.w) * inv;
    }
    __syncthreads();

    // Projection: 224 threads; thread = o*16 + chunk; each chunk covers 32 d's.
    if (t < NOSC * 16) {
        const int o  = t >> 4;
        const int ch = t & 15;
        float p = 0.f;
#pragma unroll 8
        for (int d = ch * 32; d < ch * 32 + 32; ++d)
            p += meanv[d] * W_in[d * NOSC + o];
        pp[o][ch] = p;
    }
    __syncthreads();

    if (t < NPAD) {
        float sum = 0.f;
        if (t < NOSC) {
            sum = b_in[t];
#pragma unroll
            for (int ch = 0; ch < 16; ++ch) sum += pp[t][ch];
        }
        theta0[(size_t)b * NPAD + t] = sum;
    }
}

// ---------------- Kernel 2: 100-step Kuramoto + readout + log_softmax -------
// 16 lanes per row; 14 active oscillators. Mean-field sums via 16-lane xor tree.
__global__ __launch_bounds__(256)
void kuramoto_kernel(const float* __restrict__ theta0,
                     const float* __restrict__ omega,
                     const float* __restrict__ Wc,
                     const float* __restrict__ bc,
                     float* __restrict__ out, int B)
{
    const int tid = blockIdx.x * blockDim.x + threadIdx.x;
    const int row = tid >> 4;
    const int o   = tid & 15;
    if (row >= B) return;

    const bool  act  = (o < NOSC);
    const float mask = act ? 1.0f : 0.0f;
    const int   oc   = (o < NOSC) ? o : (NOSC - 1);   // clamped index (no OOB reads)

    float theta = theta0[(size_t)row * NPAD + o];      // slot o<16 always valid (padded)
    const float drift = 6.283185307179586f * omega[oc]; // 2*pi*omega
    const float kn = 1.5f / (float)NOSC;
    const float dt = 0.01f;

    for (int it = 0; it < NSTEP; ++it) {
        float s_, c_;
        sincosf(theta, &s_, &c_);
        s_ *= mask;
        c_ *= mask;
        float S = s_, C = c_;
        S += __shfl_xor(S, 1);  C += __shfl_xor(C, 1);
        S += __shfl_xor(S, 2);  C += __shfl_xor(C, 2);
        S += __shfl_xor(S, 4);  C += __shfl_xor(C, 4);
        S += __shfl_xor(S, 8);  C += __shfl_xor(C, 8);
        const float dth = drift + kn * (S * c_ - C * s_);
        theta += dt * dth;
    }

    const float h  = cosf(theta) * mask;
    float z0 = h * Wc[oc * 2 + 0];
    float z1 = h * Wc[oc * 2 + 1];
    z0 += __shfl_xor(z0, 1);  z1 += __shfl_xor(z1, 1);
    z0 += __shfl_xor(z0, 2);  z1 += __shfl_xor(z1, 2);
    z0 += __shfl_xor(z0, 4);  z1 += __shfl_xor(z1, 4);
    z0 += __shfl_xor(z0, 8);  z1 += __shfl_xor(z1, 8);

    if (o == 0) {
        z0 += bc[0];
        z1 += bc[1];
        const float mx  = fmaxf(z0, z1);
        const float lse = mx + logf(expf(z0 - mx) + expf(z1 - mx));
        out[(size_t)row * 2 + 0] = z0 - lse;
        out[(size_t)row * 2 + 1] = z1 - lse;
    }
}

extern "C" void kernel_launch(void* const* d_in, const int* in_sizes, int n_in,
                              void* d_out, int out_size, void* d_ws, size_t ws_size,
                              hipStream_t stream)
{
    const float* x     = (const float*)d_in[0];
    const float* W_in  = (const float*)d_in[1];
    const float* b_in  = (const float*)d_in[2];
    const float* omega = (const float*)d_in[3];
    const float* Wc    = (const float*)d_in[4];
    const float* bc    = (const float*)d_in[5];
    float* out = (float*)d_out;

    const int B = in_sizes[0] / (SEQ * DIM);   // 4096

    float* theta0 = (float*)d_ws;              // B * 16 floats = 256 KiB

    pool_proj_kernel<<<B, 256, 0, stream>>>(x, W_in, b_in, theta0);

    const int total = B * NPAD;
    kuramoto_kernel<<<(total + 255) / 256, 256, 0, stream>>>(theta0, omega, Wc, bc, out, B);
}

// Round 2
// 128.820 us; speedup vs baseline: 1.0563x; 1.0563x over previous
//
#include <hip/hip_runtime.h>
#include <math.h>

#define SEQ   64
#define DIM   512
#define NOSC  14
#define NSTEP 100

typedef float f4 __attribute__((ext_vector_type(4)));

// Fused: mean-pool over tokens + projection + 100-step Kuramoto + readout.
// One block per batch row, 256 threads.
//   Phase 1: threads t: f = t&127 (float4 feature chunk), shalf = t>>7.
//            Each thread sums 32 tokens of its chunk (coalesced, nontemporal).
//   Phase 2: 224 threads compute partial dots with W_in (L2-resident).
//   Phase 3: 16 threads (quarter of wave 0) run the serial Kuramoto scan with
//            16-lane shuffle mean-field reduction, then log-softmax readout.
// The serial tail (~6 us dep chain) is hidden by other resident blocks' loads.
__global__ __launch_bounds__(256)
void fused_kernel(const float* __restrict__ x,
                  const float* __restrict__ W_in,
                  const float* __restrict__ b_in,
                  const float* __restrict__ omega,
                  const float* __restrict__ Wc,
                  const float* __restrict__ bc,
                  float* __restrict__ out)
{
    const int b = blockIdx.x;
    const int t = threadIdx.x;
    const int f = t & 127;
    const int shalf = t >> 7;

    const f4* xv = reinterpret_cast<const f4*>(x + (size_t)b * (SEQ * DIM));

    f4 acc = (f4)(0.0f);
    const int s0 = shalf * 32;
#pragma unroll 8
    for (int s = s0; s < s0 + 32; ++s) {
        f4 v = __builtin_nontemporal_load(&xv[s * (DIM / 4) + f]);
        acc += v;
    }

    __shared__ float meanv[DIM];
    __shared__ f4    part[128];
    __shared__ float pp[NOSC][16];

    if (shalf == 1) part[f] = acc;
    __syncthreads();
    if (shalf == 0) {
        f4 o = part[f];
        const float inv = 1.0f / (float)SEQ;
        meanv[4 * f + 0] = (acc[0] + o[0]) * inv;
        meanv[4 * f + 1] = (acc[1] + o[1]) * inv;
        meanv[4 * f + 2] = (acc[2] + o[2]) * inv;
        meanv[4 * f + 3] = (acc[3] + o[3]) * inv;
    }
    __syncthreads();

    // Projection: 224 threads; thread = o*16 + chunk; each chunk covers 32 d's.
    if (t < NOSC * 16) {
        const int o  = t >> 4;
        const int ch = t & 15;
        float p = 0.f;
#pragma unroll 8
        for (int d = ch * 32; d < ch * 32 + 32; ++d)
            p += meanv[d] * W_in[d * NOSC + o];
        pp[o][ch] = p;
    }
    __syncthreads();

    if (t >= 16) return;   // no more barriers below; rest of block is done

    const int  o    = t;                       // 0..15, oscillators 0..13 active
    const bool act  = (o < NOSC);
    const float mask = act ? 1.0f : 0.0f;
    const int   oc   = act ? o : (NOSC - 1);   // clamped (no OOB reads)

    float theta = 0.0f;
    if (act) {
        theta = b_in[o];
#pragma unroll
        for (int ch = 0; ch < 16; ++ch) theta += pp[o][ch];
    }

    const float drift = 6.283185307179586f * omega[oc];  // 2*pi*omega
    const float kn = 1.5f / (float)NOSC;
    const float dt = 0.01f;

    for (int it = 0; it < NSTEP; ++it) {
        float s_, c_;
        sincosf(theta, &s_, &c_);
        s_ *= mask;
        c_ *= mask;
        float S = s_, C = c_;
        S += __shfl_xor(S, 1);  C += __shfl_xor(C, 1);
        S += __shfl_xor(S, 2);  C += __shfl_xor(C, 2);
        S += __shfl_xor(S, 4);  C += __shfl_xor(C, 4);
        S += __shfl_xor(S, 8);  C += __shfl_xor(C, 8);
        const float dth = drift + kn * (S * c_ - C * s_);
        theta += dt * dth;
    }

    const float h  = cosf(theta) * mask;
    float z0 = h * Wc[oc * 2 + 0];
    float z1 = h * Wc[oc * 2 + 1];
    z0 += __shfl_xor(z0, 1);  z1 += __shfl_xor(z1, 1);
    z0 += __shfl_xor(z0, 2);  z1 += __shfl_xor(z1, 2);
    z0 += __shfl_xor(z0, 4);  z1 += __shfl_xor(z1, 4);
    z0 += __shfl_xor(z0, 8);  z1 += __shfl_xor(z1, 8);

    if (o == 0) {
        z0 += bc[0];
        z1 += bc[1];
        const float mx  = fmaxf(z0, z1);
        const float lse = mx + logf(expf(z0 - mx) + expf(z1 - mx));
        out[(size_t)b * 2 + 0] = z0 - lse;
        out[(size_t)b * 2 + 1] = z1 - lse;
    }
}

extern "C" void kernel_launch(void* const* d_in, const int* in_sizes, int n_in,
                              void* d_out, int out_size, void* d_ws, size_t ws_size,
                              hipStream_t stream)
{
    const float* x     = (const float*)d_in[0];
    const float* W_in  = (const float*)d_in[1];
    const float* b_in  = (const float*)d_in[2];
    const float* omega = (const float*)d_in[3];
    const float* Wc    = (const float*)d_in[4];
    const float* bc    = (const float*)d_in[5];
    float* out = (float*)d_out;

    const int B = in_sizes[0] / (SEQ * DIM);   // 4096

    fused_kernel<<<B, 256, 0, stream>>>(x, W_in, b_in, omega, Wc, bc, out);
}

// Round 3
// 107.224 us; speedup vs baseline: 1.2691x; 1.2014x over previous
//
#include <hip/hip_runtime.h>
#include <math.h>

#define SEQ   64
#define DIM   512
#define NOSC  14
#define NSTEP 100

typedef float f4 __attribute__((ext_vector_type(4)));

// 16-lane sum + broadcast using pure-VALU DPP (no LDS shuffle latency):
//   xor1  = quad_perm [1,0,3,2] = 0xB1
//   xor2  = quad_perm [2,3,0,1] = 0x4E
//   cross-quad within 8  = row_half_mirror (0x141)
//   cross-8 within 16    = row_mirror      (0x140)
__device__ __forceinline__ float dpp_sum16(float v) {
    v += __int_as_float(__builtin_amdgcn_update_dpp(0, __float_as_int(v), 0xB1,  0xF, 0xF, true));
    v += __int_as_float(__builtin_amdgcn_update_dpp(0, __float_as_int(v), 0x4E,  0xF, 0xF, true));
    v += __int_as_float(__builtin_amdgcn_update_dpp(0, __float_as_int(v), 0x141, 0xF, 0xF, true));
    v += __int_as_float(__builtin_amdgcn_update_dpp(0, __float_as_int(v), 0x140, 0xF, 0xF, true));
    return v;
}

// HW trig: v_sin_f32 / v_cos_f32 take REVOLUTIONS; reduce with fract first.
__device__ __forceinline__ void fast_sincos(float theta, float* s, float* c) {
    const float inv2pi = 0.15915494309189535f;
    float r = theta * inv2pi;
    r = r - floorf(r);                 // v_fract
    *s = __builtin_amdgcn_sinf(r);     // sin(2*pi*r)
    *c = __builtin_amdgcn_cosf(r);
}

// Fused: mean-pool over tokens + projection + 100-step Kuramoto + readout.
// One block per batch row, 256 threads.
__global__ __launch_bounds__(256)
void fused_kernel(const float* __restrict__ x,
                  const float* __restrict__ W_in,
                  const float* __restrict__ b_in,
                  const float* __restrict__ omega,
                  const float* __restrict__ Wc,
                  const float* __restrict__ bc,
                  float* __restrict__ out)
{
    const int b = blockIdx.x;
    const int t = threadIdx.x;
    const int f = t & 127;
    const int shalf = t >> 7;

    const f4* xv = reinterpret_cast<const f4*>(x + (size_t)b * (SEQ * DIM));

    f4 acc = (f4)(0.0f);
    const int s0 = shalf * 32;
#pragma unroll 8
    for (int s = s0; s < s0 + 32; ++s) {
        f4 v = __builtin_nontemporal_load(&xv[s * (DIM / 4) + f]);
        acc += v;
    }

    __shared__ float meanv[DIM];
    __shared__ f4    part[128];
    __shared__ float pp[NOSC][16];

    if (shalf == 1) part[f] = acc;
    __syncthreads();
    if (shalf == 0) {
        f4 o = part[f];
        const float inv = 1.0f / (float)SEQ;
        meanv[4 * f + 0] = (acc[0] + o[0]) * inv;
        meanv[4 * f + 1] = (acc[1] + o[1]) * inv;
        meanv[4 * f + 2] = (acc[2] + o[2]) * inv;
        meanv[4 * f + 3] = (acc[3] + o[3]) * inv;
    }
    __syncthreads();

    // Projection: 224 threads; thread = o*16 + chunk; each chunk covers 32 d's.
    if (t < NOSC * 16) {
        const int o  = t >> 4;
        const int ch = t & 15;
        float p = 0.f;
#pragma unroll 8
        for (int d = ch * 32; d < ch * 32 + 32; ++d)
            p += meanv[d] * W_in[d * NOSC + o];
        pp[o][ch] = p;
    }
    __syncthreads();

    if (t >= 16) return;   // waves 1-3 exit; 16 lanes of wave 0 run the scan

    const int  o    = t;                       // 0..15, oscillators 0..13 active
    const bool act  = (o < NOSC);
    const float mask = act ? 1.0f : 0.0f;
    const int   oc   = act ? o : (NOSC - 1);   // clamped (no OOB reads)

    float theta = 0.0f;
    if (act) {
        theta = b_in[o];
#pragma unroll
        for (int ch = 0; ch < 16; ++ch) theta += pp[o][ch];
    }

    const float drift = 6.283185307179586f * omega[oc];  // 2*pi*omega
    const float kn = 1.5f / (float)NOSC;
    const float dt = 0.01f;

    for (int it = 0; it < NSTEP; ++it) {
        float s_, c_;
        fast_sincos(theta, &s_, &c_);
        s_ *= mask;
        c_ *= mask;
        const float S = dpp_sum16(s_);
        const float C = dpp_sum16(c_);
        theta += dt * (drift + kn * (S * c_ - C * s_));
    }

    float hs, hc;
    fast_sincos(theta, &hs, &hc);
    const float h = hc * mask;
    float z0 = dpp_sum16(h * Wc[oc * 2 + 0]);
    float z1 = dpp_sum16(h * Wc[oc * 2 + 1]);

    if (o == 0) {
        z0 += bc[0];
        z1 += bc[1];
        const float mx  = fmaxf(z0, z1);
        const float lse = mx + logf(expf(z0 - mx) + expf(z1 - mx));
        out[(size_t)b * 2 + 0] = z0 - lse;
        out[(size_t)b * 2 + 1] = z1 - lse;
    }
}

extern "C" void kernel_launch(void* const* d_in, const int* in_sizes, int n_in,
                              void* d_out, int out_size, void* d_ws, size_t ws_size,
                              hipStream_t stream)
{
    const float* x     = (const float*)d_in[0];
    const float* W_in  = (const float*)d_in[1];
    const float* b_in  = (const float*)d_in[2];
    const float* omega = (const float*)d_in[3];
    const float* Wc    = (const float*)d_in[4];
    const float* bc    = (const float*)d_in[5];
    float* out = (float*)d_out;

    const int B = in_sizes[0] / (SEQ * DIM);   // 4096

    fused_kernel<<<B, 256, 0, stream>>>(x, W_in, b_in, omega, Wc, bc, out);
}

// Round 4
// 100.130 us; speedup vs baseline: 1.3590x; 1.0708x over previous
//
#include <hip/hip_runtime.h>
#include <math.h>

#define SEQ   64
#define DIM   512
#define NOSC  14
#define NSTEP 100
#define RPB   2     // rows per block

typedef float f4 __attribute__((ext_vector_type(4)));

// 16-lane sum + broadcast using pure-VALU DPP:
//   quad_perm xor1 = 0xB1, xor2 = 0x4E, row_half_mirror = 0x141, row_mirror = 0x140
__device__ __forceinline__ float dpp_sum16(float v) {
    v += __int_as_float(__builtin_amdgcn_update_dpp(0, __float_as_int(v), 0xB1,  0xF, 0xF, true));
    v += __int_as_float(__builtin_amdgcn_update_dpp(0, __float_as_int(v), 0x4E,  0xF, 0xF, true));
    v += __int_as_float(__builtin_amdgcn_update_dpp(0, __float_as_int(v), 0x141, 0xF, 0xF, true));
    v += __int_as_float(__builtin_amdgcn_update_dpp(0, __float_as_int(v), 0x140, 0xF, 0xF, true));
    return v;
}

// HW trig: v_sin_f32 / v_cos_f32 take REVOLUTIONS; reduce with fract first.
__device__ __forceinline__ void fast_sincos(float theta, float* s, float* c) {
    const float inv2pi = 0.15915494309189535f;
    float r = theta * inv2pi;
    r = r - floorf(r);
    *s = __builtin_amdgcn_sinf(r);
    *c = __builtin_amdgcn_cosf(r);
}

// Fused, block-pipelined: each block owns RPB rows.
//   waves 0-1 (128 thr): load+pool row r+1 (1 float4 chunk per thread, 64 tokens)
//   wave 3 lanes 0-15:   Kuramoto scan + readout for row r (concurrently)
//   projection: 224 threads, between barriers. mv double-buffered.
__global__ __launch_bounds__(256, 8)
void fused_kernel(const float* __restrict__ x,
                  const float* __restrict__ W_in,
                  const float* __restrict__ b_in,
                  const float* __restrict__ omega,
                  const float* __restrict__ Wc,
                  const float* __restrict__ bc,
                  float* __restrict__ out, int B)
{
    const int t    = threadIdx.x;
    const int row0 = blockIdx.x * RPB;

    __shared__ f4    mv[2][DIM / 4];   // pooled mean vectors (double-buffered)
    __shared__ float pp[NOSC][16];     // projection partials

    // ---- prologue: load+pool row0 -> mv[0]
    if (t < 128 && row0 < B) {
        const f4* xv = reinterpret_cast<const f4*>(x + (size_t)row0 * (SEQ * DIM));
        f4 acc = (f4)(0.0f);
#pragma unroll 4
        for (int s = 0; s < SEQ; ++s)
            acc += __builtin_nontemporal_load(&xv[s * (DIM / 4) + t]);
        mv[0][t] = acc * (1.0f / SEQ);
    }
    __syncthreads();
    {   // ---- project row0 -> pp (conflict-free: 16 ch-lanes read consecutive floats)
        const float* m = reinterpret_cast<const float*>(mv[0]);
        if (t < NOSC * 16) {
            const int o  = t >> 4;
            const int ch = t & 15;
            float p = 0.f;
#pragma unroll 8
            for (int i = 0; i < 32; ++i) {
                const int d = i * 16 + ch;
                p += m[d] * W_in[d * NOSC + o];
            }
            pp[o][ch] = p;
        }
    }
    __syncthreads();

    for (int r = 0; r < RPB; ++r) {
        const int nb = (r & 1) ^ 1;    // buffer for next row
        if (t >= 192) {
            // ---- wave 3, lanes 0-15: scan row0+r while waves 0-1 load row r+1
            const int lane = t - 192;
            const int row  = row0 + r;
            if (lane < 16 && row < B) {
                const bool  act  = (lane < NOSC);
                const float mask = act ? 1.0f : 0.0f;
                const int   oc   = act ? lane : (NOSC - 1);

                float theta = 0.0f;
                if (act) {
                    theta = b_in[lane];
#pragma unroll
                    for (int ch = 0; ch < 16; ++ch) theta += pp[lane][ch];
                }
                const float drift = 6.283185307179586f * omega[oc];
                const float kn = 1.5f / (float)NOSC;
                const float dt = 0.01f;

                for (int it = 0; it < NSTEP; ++it) {
                    float s_, c_;
                    fast_sincos(theta, &s_, &c_);
                    s_ *= mask; c_ *= mask;
                    const float S = dpp_sum16(s_);
                    const float C = dpp_sum16(c_);
                    theta += dt * (drift + kn * (S * c_ - C * s_));
                }

                float hs, hc;
                fast_sincos(theta, &hs, &hc);
                const float h = hc * mask;
                float z0 = dpp_sum16(h * Wc[oc * 2 + 0]);
                float z1 = dpp_sum16(h * Wc[oc * 2 + 1]);
                if (lane == 0) {
                    z0 += bc[0]; z1 += bc[1];
                    const float mx  = fmaxf(z0, z1);
                    const float lse = mx + logf(expf(z0 - mx) + expf(z1 - mx));
                    out[(size_t)row * 2 + 0] = z0 - lse;
                    out[(size_t)row * 2 + 1] = z1 - lse;
                }
            }
        } else if (t < 128 && r + 1 < RPB && row0 + r + 1 < B) {
            // ---- waves 0-1: load+pool next row -> mv[nb]
            const f4* xv = reinterpret_cast<const f4*>(x + (size_t)(row0 + r + 1) * (SEQ * DIM));
            f4 acc = (f4)(0.0f);
#pragma unroll 4
            for (int s = 0; s < SEQ; ++s)
                acc += __builtin_nontemporal_load(&xv[s * (DIM / 4) + t]);
            mv[nb][t] = acc * (1.0f / SEQ);
        }
        __syncthreads();
        if (r + 1 < RPB) {
            // pp is free now (scan r finished before the barrier)
            const float* m = reinterpret_cast<const float*>(mv[nb]);
            if (t < NOSC * 16) {
                const int o  = t >> 4;
                const int ch = t & 15;
                float p = 0.f;
#pragma unroll 8
                for (int i = 0; i < 32; ++i) {
                    const int d = i * 16 + ch;
                    p += m[d] * W_in[d * NOSC + o];
                }
                pp[o][ch] = p;
            }
        }
        __syncthreads();
    }
}

extern "C" void kernel_launch(void* const* d_in, const int* in_sizes, int n_in,
                              void* d_out, int out_size, void* d_ws, size_t ws_size,
                              hipStream_t stream)
{
    const float* x     = (const float*)d_in[0];
    const float* W_in  = (const float*)d_in[1];
    const float* b_in  = (const float*)d_in[2];
    const float* omega = (const float*)d_in[3];
    const float* Wc    = (const float*)d_in[4];
    const float* bc    = (const float*)d_in[5];
    float* out = (float*)d_out;

    const int B = in_sizes[0] / (SEQ * DIM);   // 4096

    const int grid = (B + RPB - 1) / RPB;      // 2048 = 8 blocks/CU x 256 CU
    fused_kernel<<<grid, 256, 0, stream>>>(x, W_in, b_in, omega, Wc, bc, out, B);
}

// Round 5
// 98.337 us; speedup vs baseline: 1.3838x; 1.0182x over previous
//
#include <hip/hip_runtime.h>
#include <math.h>

#define SEQ   64
#define DIM   512
#define NOSC  14
#define NSTEP 100
#define RPB   4     // rows per block

typedef float f4 __attribute__((ext_vector_type(4)));

// 16-lane sum + broadcast using pure-VALU DPP:
//   quad_perm xor1 = 0xB1, xor2 = 0x4E, row_half_mirror = 0x141, row_mirror = 0x140
__device__ __forceinline__ float dpp_sum16(float v) {
    v += __int_as_float(__builtin_amdgcn_update_dpp(0, __float_as_int(v), 0xB1,  0xF, 0xF, true));
    v += __int_as_float(__builtin_amdgcn_update_dpp(0, __float_as_int(v), 0x4E,  0xF, 0xF, true));
    v += __int_as_float(__builtin_amdgcn_update_dpp(0, __float_as_int(v), 0x141, 0xF, 0xF, true));
    v += __int_as_float(__builtin_amdgcn_update_dpp(0, __float_as_int(v), 0x140, 0xF, 0xF, true));
    return v;
}

// HW trig: v_sin_f32 / v_cos_f32 take REVOLUTIONS; reduce with fract first.
__device__ __forceinline__ void fast_sincos(float theta, float* s, float* c) {
    const float inv2pi = 0.15915494309189535f;
    float r = theta * inv2pi;
    r = r - floorf(r);
    *s = __builtin_amdgcn_sinf(r);
    *c = __builtin_amdgcn_cosf(r);
}

// Fused, block-pipelined: each block owns RPB rows.
//   waves 0-1 (128 thr): load+pool row r+1 (1 float4 chunk per thread, 64 tokens)
//   wave 3 lanes 0-15:   Kuramoto scan + readout for row r (concurrently)
//   projection: 224 threads, between barriers. mv double-buffered.
// 4 blocks/CU (grid 1024), launch_bounds(256,4) -> 128 VGPR budget, unroll 8
// gives 8 in-flight float4 loads per thread.
__global__ __launch_bounds__(256, 4)
void fused_kernel(const float* __restrict__ x,
                  const float* __restrict__ W_in,
                  const float* __restrict__ b_in,
                  const float* __restrict__ omega,
                  const float* __restrict__ Wc,
                  const float* __restrict__ bc,
                  float* __restrict__ out, int B)
{
    const int t    = threadIdx.x;
    const int row0 = blockIdx.x * RPB;

    __shared__ f4    mv[2][DIM / 4];   // pooled mean vectors (double-buffered)
    __shared__ float pp[NOSC][16];     // projection partials

    // ---- prologue: load+pool row0 -> mv[0]
    if (t < 128 && row0 < B) {
        const f4* xv = reinterpret_cast<const f4*>(x + (size_t)row0 * (SEQ * DIM));
        f4 acc = (f4)(0.0f);
#pragma unroll 8
        for (int s = 0; s < SEQ; ++s)
            acc += __builtin_nontemporal_load(&xv[s * (DIM / 4) + t]);
        mv[0][t] = acc * (1.0f / SEQ);
    }
    __syncthreads();
    {   // ---- project row0 -> pp (conflict-free: 16 ch-lanes read consecutive floats)
        const float* m = reinterpret_cast<const float*>(mv[0]);
        if (t < NOSC * 16) {
            const int o  = t >> 4;
            const int ch = t & 15;
            float p = 0.f;
#pragma unroll 8
            for (int i = 0; i < 32; ++i) {
                const int d = i * 16 + ch;
                p += m[d] * W_in[d * NOSC + o];
            }
            pp[o][ch] = p;
        }
    }
    __syncthreads();

    for (int r = 0; r < RPB; ++r) {
        const int nb = (r & 1) ^ 1;    // buffer for next row
        if (t >= 192) {
            // ---- wave 3, lanes 0-15: scan row0+r while waves 0-1 load row r+1
            const int lane = t - 192;
            const int row  = row0 + r;
            if (lane < 16 && row < B) {
                const bool  act  = (lane < NOSC);
                const float mask = act ? 1.0f : 0.0f;
                const int   oc   = act ? lane : (NOSC - 1);

                float theta = 0.0f;
                if (act) {
                    theta = b_in[lane];
#pragma unroll
                    for (int ch = 0; ch < 16; ++ch) theta += pp[lane][ch];
                }
                const float drift = 6.283185307179586f * omega[oc];
                const float kn = 1.5f / (float)NOSC;
                const float dt = 0.01f;

                for (int it = 0; it < NSTEP; ++it) {
                    float s_, c_;
                    fast_sincos(theta, &s_, &c_);
                    s_ *= mask; c_ *= mask;
                    const float S = dpp_sum16(s_);
                    const float C = dpp_sum16(c_);
                    theta += dt * (drift + kn * (S * c_ - C * s_));
                }

                float hs, hc;
                fast_sincos(theta, &hs, &hc);
                const float h = hc * mask;
                float z0 = dpp_sum16(h * Wc[oc * 2 + 0]);
                float z1 = dpp_sum16(h * Wc[oc * 2 + 1]);
                if (lane == 0) {
                    z0 += bc[0]; z1 += bc[1];
                    const float mx  = fmaxf(z0, z1);
                    const float lse = mx + logf(expf(z0 - mx) + expf(z1 - mx));
                    out[(size_t)row * 2 + 0] = z0 - lse;
                    out[(size_t)row * 2 + 1] = z1 - lse;
                }
            }
        } else if (t < 128 && r + 1 < RPB && row0 + r + 1 < B) {
            // ---- waves 0-1: load+pool next row -> mv[nb]
            const f4* xv = reinterpret_cast<const f4*>(x + (size_t)(row0 + r + 1) * (SEQ * DIM));
            f4 acc = (f4)(0.0f);
#pragma unroll 8
            for (int s = 0; s < SEQ; ++s)
                acc += __builtin_nontemporal_load(&xv[s * (DIM / 4) + t]);
            mv[nb][t] = acc * (1.0f / SEQ);
        }
        __syncthreads();
        if (r + 1 < RPB) {
            // pp is free now (scan r finished before the barrier)
            const float* m = reinterpret_cast<const float*>(mv[nb]);
            if (t < NOSC * 16) {
                const int o  = t >> 4;
                const int ch = t & 15;
                float p = 0.f;
#pragma unroll 8
                for (int i = 0; i < 32; ++i) {
                    const int d = i * 16 + ch;
                    p += m[d] * W_in[d * NOSC + o];
                }
                pp[o][ch] = p;
            }
        }
        __syncthreads();
    }
}

extern "C" void kernel_launch(void* const* d_in, const int* in_sizes, int n_in,
                              void* d_out, int out_size, void* d_ws, size_t ws_size,
                              hipStream_t stream)
{
    const float* x     = (const float*)d_in[0];
    const float* W_in  = (const float*)d_in[1];
    const float* b_in  = (const float*)d_in[2];
    const float* omega = (const float*)d_in[3];
    const float* Wc    = (const float*)d_in[4];
    const float* bc    = (const float*)d_in[5];
    float* out = (float*)d_out;

    const int B = in_sizes[0] / (SEQ * DIM);   // 4096

    const int grid = (B + RPB - 1) / RPB;      // 1024 = 4 blocks/CU x 256 CU
    fused_kernel<<<grid, 256, 0, stream>>>(x, W_in, b_in, omega, Wc, bc, out, B);
}